// Round 7
// baseline (286.490 us; speedup 1.0000x reference)
//
#include <hip/hip_runtime.h>
#include <cstddef>
#include <cstdint>

#define NNODES 50000
#define NEDGES 800000
#define FDIM   256

#define SCAN_BLOCKS 256
#define SCAN_CHUNK  ((NNODES + SCAN_BLOCKS - 1) / SCAN_BLOCKS)   // 196

typedef __attribute__((ext_vector_type(8))) _Float16 f16x8;
typedef __attribute__((ext_vector_type(8))) unsigned short ushort8;
typedef __attribute__((ext_vector_type(4))) float f32x4;

__device__ __forceinline__ float leaky_exp(float a) {
    float e = a > 0.f ? a : 0.2f * a;
    return __expf(e);
}
__device__ __forceinline__ unsigned short f2h(float f) {
    return __builtin_bit_cast(unsigned short, (_Float16)f);
}
__device__ __forceinline__ float hlo(uint32_t u) {
    _Float16 h = __builtin_bit_cast(_Float16, (unsigned short)(u & 0xffffu));
    return (float)h;
}
__device__ __forceinline__ float hhi(uint32_t u) {
    _Float16 h = __builtin_bit_cast(_Float16, (unsigned short)(u >> 16));
    return (float)h;
}
__device__ __forceinline__ float rlanef(float v, int l) {
    return __builtin_bit_cast(float,
        __builtin_amdgcn_readlane(__builtin_bit_cast(int, v), l));
}

// ---------------- fp32 -> f16 bulk convert (8 elems/thread) ----------------
__global__ __launch_bounds__(256) void cvt_k(const float* __restrict__ in,
                                             unsigned short* __restrict__ out,
                                             int n8) {
    int i = blockIdx.x * 256 + threadIdx.x;
    if (i >= n8) return;
    const float4* p = (const float4*)in + (size_t)i * 2;
    float4 a = p[0], b = p[1];
    ushort8 r;
    r[0] = f2h(a.x); r[1] = f2h(a.y); r[2] = f2h(a.z); r[3] = f2h(a.w);
    r[4] = f2h(b.x); r[5] = f2h(b.y); r[6] = f2h(b.z); r[7] = f2h(b.w);
    *(ushort8*)(out + (size_t)i * 8) = r;
}

// ------------- W[256][256] -> Wt[n][k] f16 (transpose + convert) -------------
__global__ __launch_bounds__(256) void wprep_k(const float* __restrict__ W,
                                               unsigned short* __restrict__ Wt) {
    int n = blockIdx.x, k = threadIdx.x;
    Wt[n * 256 + k] = f2h(W[k * 256 + n]);
}

// --------- f16 MFMA GEMM: C[M,256] = A[M,256] @ Bt[256,256]^T, f16 out ---------
__global__ __launch_bounds__(256) void gemm_mfma(const unsigned short* __restrict__ A,
                                                 const unsigned short* __restrict__ Bt,
                                                 unsigned short* __restrict__ C, int M) {
    __shared__ unsigned short As[128 * 64];
    __shared__ unsigned short Bs[128 * 64];
    const int t = threadIdx.x;
    const int lane = t & 63, wid = t >> 6;
    const int wr = wid >> 1, wc = wid & 1;
    const int bm = blockIdx.x * 128;
    const int bn = blockIdx.y * 128;
    f32x4 acc[4][4] = {};
    const int lrow = t >> 3, lslot = t & 7;
    for (int k0 = 0; k0 < 256; k0 += 64) {
        __syncthreads();
#pragma unroll
        for (int i = 0; i < 4; ++i) {
            int row = lrow + 32 * i;
            int ga = bm + row; ga = ga < M ? ga : M - 1;
            uint4 av = *(const uint4*)(A + (size_t)ga * FDIM + k0 + lslot * 8);
            *(uint4*)(As + row * 64 + ((lslot ^ (row & 7)) << 3)) = av;
            uint4 bv = *(const uint4*)(Bt + (size_t)(bn + row) * FDIM + k0 + lslot * 8);
            *(uint4*)(Bs + row * 64 + ((lslot ^ (row & 7)) << 3)) = bv;
        }
        __syncthreads();
#pragma unroll
        for (int ks = 0; ks < 2; ++ks) {
            const int kq = ks * 4 + (lane >> 4);
            f16x8 a[4], b[4];
#pragma unroll
            for (int f = 0; f < 4; ++f) {
                int ra = wr * 64 + f * 16 + (lane & 15);
                a[f] = *(const f16x8*)(As + ra * 64 + ((kq ^ (ra & 7)) << 3));
                int rb = wc * 64 + f * 16 + (lane & 15);
                b[f] = *(const f16x8*)(Bs + rb * 64 + ((kq ^ (rb & 7)) << 3));
            }
#pragma unroll
            for (int mf = 0; mf < 4; ++mf)
#pragma unroll
                for (int nf = 0; nf < 4; ++nf)
                    acc[mf][nf] = __builtin_amdgcn_mfma_f32_16x16x32_f16(
                        a[mf], b[nf], acc[mf][nf], 0, 0, 0);
        }
    }
    const int col0 = bn + wc * 64 + (lane & 15);
    const int row00 = bm + wr * 64 + (lane >> 4) * 4;
#pragma unroll
    for (int mf = 0; mf < 4; ++mf)
#pragma unroll
        for (int nf = 0; nf < 4; ++nf) {
            f32x4 v = acc[mf][nf];
            int col = col0 + nf * 16;
#pragma unroll
            for (int r = 0; r < 4; ++r) {
                int row = row00 + mf * 16 + r;
                if (row < M) C[(size_t)row * FDIM + col] = f2h(v[r]);
            }
        }
}

// ------------- attention logits from f16 xp; wave per node -------------
template <int H>
__global__ __launch_bounds__(256) void aprep_k(const unsigned short* __restrict__ xp,
                                               const float* __restrict__ atts,
                                               const float* __restrict__ attd,
                                               float* __restrict__ as_,
                                               float* __restrict__ ad_) {
    const int lane = threadIdx.x & 63;
    const int n = blockIdx.x * 4 + (threadIdx.x >> 6);
    if (n >= NNODES) return;
    const int c = lane << 2;
    uint2 u = *(const uint2*)(xp + (size_t)n * FDIM + c);
    float v0 = hlo(u.x), v1 = hhi(u.x), v2 = hlo(u.y), v3 = hhi(u.y);
    float4 s4 = *(const float4*)(atts + c);
    float4 d4 = *(const float4*)(attd + c);
    float ss = v0 * s4.x + v1 * s4.y + v2 * s4.z + v3 * s4.w;
    float sd = v0 * d4.x + v1 * d4.y + v2 * d4.z + v3 * d4.w;
    constexpr int G = 64 / H;
#pragma unroll
    for (int off = 1; off < G; off <<= 1) {
        ss += __shfl_xor(ss, off);
        sd += __shfl_xor(sd, off);
    }
    if ((lane & (G - 1)) == 0) {
        int h = lane / G;
        as_[n * H + h] = ss;
        ad_[n * H + h] = sd;
    }
}

// ---------------- CSR build: histogram -> 3-phase scan -> scatter ----------------
__global__ __launch_bounds__(256) void hist_k(const int* __restrict__ ei,
                                              int* __restrict__ deg) {
    int e = blockIdx.x * 256 + threadIdx.x;
    if (e < NEDGES) atomicAdd(&deg[ei[NEDGES + e]], 1);
}

__global__ __launch_bounds__(256) void scanA_k(const int* __restrict__ deg,
                                               int* __restrict__ bsum) {
    const int b = blockIdx.x, t = threadIdx.x;
    const int i = b * SCAN_CHUNK + t;
    int v = (t < SCAN_CHUNK && i < NNODES) ? deg[i] : 0;
#pragma unroll
    for (int off = 1; off < 64; off <<= 1) v += __shfl_xor(v, off);
    __shared__ int ws[4];
    if ((t & 63) == 0) ws[t >> 6] = v;
    __syncthreads();
    if (t == 0) bsum[b] = ws[0] + ws[1] + ws[2] + ws[3];
}

__global__ __launch_bounds__(256) void scanB_k(const int* __restrict__ bsum,
                                               int* __restrict__ boff,
                                               int* __restrict__ rowptr) {
    const int t = threadIdx.x;
    const int lane = t & 63, wid = t >> 6;
    int orig = bsum[t];
    int v = orig;
#pragma unroll
    for (int off = 1; off < 64; off <<= 1) {
        int u = __shfl_up(v, off);
        if (lane >= off) v += u;
    }
    __shared__ int ws[4], wo[4];
    if (lane == 63) ws[wid] = v;
    __syncthreads();
    if (t == 0) {
        int a = 0;
        for (int k = 0; k < 4; ++k) { wo[k] = a; a += ws[k]; }
        rowptr[NNODES] = a;
    }
    __syncthreads();
    boff[t] = wo[wid] + v - orig;
}

__global__ __launch_bounds__(256) void scanC_k(const int* __restrict__ deg,
                                               const int* __restrict__ boff,
                                               int* __restrict__ rowptr) {
    const int b = blockIdx.x, t = threadIdx.x;
    const int i = b * SCAN_CHUNK + t;
    const bool ok = (t < SCAN_CHUNK && i < NNODES);
    int orig = ok ? deg[i] : 0;
    int v = orig;
    const int lane = t & 63, wid = t >> 6;
#pragma unroll
    for (int off = 1; off < 64; off <<= 1) {
        int u = __shfl_up(v, off);
        if (lane >= off) v += u;
    }
    __shared__ int ws[4], wo[4];
    if (lane == 63) ws[wid] = v;
    __syncthreads();
    if (t == 0) {
        int a = 0;
        for (int k = 0; k < 4; ++k) { wo[k] = a; a += ws[k]; }
    }
    __syncthreads();
    if (ok) rowptr[i] = boff[b] + wo[wid] + v - orig;
}

__global__ __launch_bounds__(256) void scatter_k(const int* __restrict__ ei,
                                                 const int* __restrict__ rowptr,
                                                 int* __restrict__ deg,
                                                 int* __restrict__ ssrc) {
    int e = blockIdx.x * 256 + threadIdx.x;
    if (e >= NEDGES) return;
    int s = ei[e], d = ei[NEDGES + e];
    int old = atomicSub(&deg[d], 1);
    ssrc[rowptr[d + 1] - old] = s;
}

// ---- layer-1 gather (H=4): f16 rows, fma accumulate, den in weight phase ----
__global__ __launch_bounds__(256) void gather1_k(const unsigned short* __restrict__ xp,
                                                 const float* __restrict__ as_,
                                                 const float* __restrict__ ad_,
                                                 const int* __restrict__ rowptr,
                                                 const int* __restrict__ ssrc,
                                                 const float* __restrict__ bias,
                                                 unsigned short* __restrict__ out) {
    const int lane = threadIdx.x & 63;
    const int n = blockIdx.x * 4 + (threadIdx.x >> 6);
    if (n >= NNODES) return;
    const int h = lane >> 4;            // head for feature lanes
    const int c = lane << 2;
    const int eloc = lane >> 2;         // strip edge slot (0..15)
    const int hh = lane & 3;            // strip head slot
    const float adW = ad_[n * 4 + hh];
    float a0 = 0.f, a1 = 0.f, a2 = 0.f, a3 = 0.f, den = 0.f;
    const int beg = rowptr[n], end = rowptr[n + 1];
    for (int base = beg; base < end; base += 16) {
        int my_e = base + eloc;
        float wv = 0.f; int sv = 0;
        if (my_e < end) {
            sv = ssrc[my_e];
            wv = leaky_exp(as_[sv * 4 + hh] + adW);
        }
        // strip denominator: reduce wv over eloc (offsets 4..32 keep hh classes)
        float dred = wv;
#pragma unroll
        for (int off = 4; off < 64; off <<= 1) dred += __shfl_xor(dred, off);
        den += __shfl(dred, h);          // lane h holds hh==h sum
        const int cnt = min(16, end - base);
        int e = 0;
        for (; e + 8 <= cnt; e += 8) {
            uint2 u[8]; float w[8];
#pragma unroll
            for (int q = 0; q < 8; ++q) {
                int sq = __builtin_amdgcn_readlane(sv, (e + q) << 2);
                u[q] = *(const uint2*)(xp + (((unsigned)sq << 8) + (unsigned)c));
                w[q] = __shfl(wv, ((e + q) << 2) | h);
            }
#pragma unroll
            for (int q = 0; q < 8; ++q) {
                a0 = fmaf(hlo(u[q].x), w[q], a0);
                a1 = fmaf(hhi(u[q].x), w[q], a1);
                a2 = fmaf(hlo(u[q].y), w[q], a2);
                a3 = fmaf(hhi(u[q].y), w[q], a3);
            }
        }
        for (; e < cnt; ++e) {
            int sq = __builtin_amdgcn_readlane(sv, e << 2);
            uint2 u0 = *(const uint2*)(xp + (((unsigned)sq << 8) + (unsigned)c));
            float w0 = __shfl(wv, (e << 2) | h);
            a0 = fmaf(hlo(u0.x), w0, a0); a1 = fmaf(hhi(u0.x), w0, a1);
            a2 = fmaf(hlo(u0.y), w0, a2); a3 = fmaf(hhi(u0.y), w0, a3);
        }
    }
    {   // self loop
        float w = leaky_exp(as_[n * 4 + h] + ad_[n * 4 + h]);
        uint2 u = *(const uint2*)(xp + (((unsigned)n << 8) + (unsigned)c));
        a0 = fmaf(hlo(u.x), w, a0); a1 = fmaf(hhi(u.x), w, a1);
        a2 = fmaf(hlo(u.y), w, a2); a3 = fmaf(hhi(u.y), w, a3);
        den += w;
    }
    const float inv = 1.f / (den + 1e-16f);
    float4 b4 = *(const float4*)(bias + c);
    float o[4] = {a0 * inv + b4.x, a1 * inv + b4.y,
                  a2 * inv + b4.z, a3 * inv + b4.w};
#pragma unroll
    for (int j = 0; j < 4; ++j) o[j] = o[j] > 0.f ? o[j] : __expf(o[j]) - 1.f;
    ushort4 r;
    r.x = f2h(o[0]); r.y = f2h(o[1]); r.z = f2h(o[2]); r.w = f2h(o[3]);
    *(ushort4*)(out + (size_t)n * FDIM + c) = r;
}

// ---- layer-2 gather (H=1): 64-edge strips, readlane weights; +BN+LN ----
__global__ __launch_bounds__(256) void gather2_k(const unsigned short* __restrict__ xp,
                                                 const float* __restrict__ as_,
                                                 const float* __restrict__ ad_,
                                                 const int* __restrict__ rowptr,
                                                 const int* __restrict__ ssrc,
                                                 const float* __restrict__ bias,
                                                 const float* __restrict__ bng,
                                                 const float* __restrict__ bnb,
                                                 const float* __restrict__ bnm,
                                                 const float* __restrict__ bnv,
                                                 const float* __restrict__ lng,
                                                 const float* __restrict__ lnb,
                                                 float* __restrict__ out) {
    const int lane = threadIdx.x & 63;
    const int n = blockIdx.x * 4 + (threadIdx.x >> 6);
    if (n >= NNODES) return;
    const int c = lane << 2;
    const float adn = ad_[n];
    float a0 = 0.f, a1 = 0.f, a2 = 0.f, a3 = 0.f, den = 0.f;
    const int beg = rowptr[n], end = rowptr[n + 1];
    for (int base = beg; base < end; base += 64) {
        int my_e = base + lane;
        float wv = 0.f; int sv = 0;
        if (my_e < end) {
            sv = ssrc[my_e];
            wv = leaky_exp(as_[sv] + adn);
        }
        float dred = wv;
#pragma unroll
        for (int off = 1; off < 64; off <<= 1) dred += __shfl_xor(dred, off);
        den += dred;
        const int cnt = min(64, end - base);
        int e = 0;
        for (; e + 8 <= cnt; e += 8) {
            uint2 u[8]; float w[8];
#pragma unroll
            for (int q = 0; q < 8; ++q) {
                int sq = __builtin_amdgcn_readlane(sv, e + q);
                u[q] = *(const uint2*)(xp + (((unsigned)sq << 8) + (unsigned)c));
                w[q] = rlanef(wv, e + q);
            }
#pragma unroll
            for (int q = 0; q < 8; ++q) {
                a0 = fmaf(hlo(u[q].x), w[q], a0);
                a1 = fmaf(hhi(u[q].x), w[q], a1);
                a2 = fmaf(hlo(u[q].y), w[q], a2);
                a3 = fmaf(hhi(u[q].y), w[q], a3);
            }
        }
        for (; e < cnt; ++e) {
            int sq = __builtin_amdgcn_readlane(sv, e);
            uint2 u0 = *(const uint2*)(xp + (((unsigned)sq << 8) + (unsigned)c));
            float w0 = rlanef(wv, e);
            a0 = fmaf(hlo(u0.x), w0, a0); a1 = fmaf(hhi(u0.x), w0, a1);
            a2 = fmaf(hlo(u0.y), w0, a2); a3 = fmaf(hhi(u0.y), w0, a3);
        }
    }
    {   // self loop
        float w = leaky_exp(as_[n] + adn);
        uint2 u = *(const uint2*)(xp + (((unsigned)n << 8) + (unsigned)c));
        a0 = fmaf(hlo(u.x), w, a0); a1 = fmaf(hhi(u.x), w, a1);
        a2 = fmaf(hlo(u.y), w, a2); a3 = fmaf(hhi(u.y), w, a3);
        den += w;
    }
    const float inv = 1.f / (den + 1e-16f);
    float vals[4] = {a0 * inv, a1 * inv, a2 * inv, a3 * inv};
#pragma unroll
    for (int j = 0; j < 4; ++j) {
        float o = vals[j] + bias[c + j];
        o = o > 0.f ? o : __expf(o) - 1.f;                             // ELU
        o = (o - bnm[c + j]) * rsqrtf(bnv[c + j] + 1e-5f) * bng[c + j]
            + bnb[c + j];                                              // BN
        vals[j] = o;
    }
    float s1 = vals[0] + vals[1] + vals[2] + vals[3];
    float s2 = vals[0] * vals[0] + vals[1] * vals[1] +
               vals[2] * vals[2] + vals[3] * vals[3];
#pragma unroll
    for (int off = 1; off < 64; off <<= 1) {
        s1 += __shfl_xor(s1, off);
        s2 += __shfl_xor(s2, off);
    }
    float mu  = s1 * (1.f / 256.f);
    float var = s2 * (1.f / 256.f) - mu * mu;
    float r   = rsqrtf(var + 1e-5f);
#pragma unroll
    for (int j = 0; j < 4; ++j)
        out[(size_t)n * FDIM + c + j] = (vals[j] - mu) * r * lng[c + j] + lnb[c + j];
}

extern "C" void kernel_launch(void* const* d_in, const int* in_sizes, int n_in,
                              void* d_out, int out_size, void* d_ws, size_t ws_size,
                              hipStream_t stream) {
    const float* x      = (const float*)d_in[0];
    const int*   ei     = (const int*)d_in[1];
    const float* W1     = (const float*)d_in[2];
    const float* atts1  = (const float*)d_in[3];
    const float* attd1  = (const float*)d_in[4];
    const float* bias1  = (const float*)d_in[5];
    const float* W2     = (const float*)d_in[6];
    const float* atts2  = (const float*)d_in[7];
    const float* attd2  = (const float*)d_in[8];
    const float* bias2  = (const float*)d_in[9];
    const float* bng    = (const float*)d_in[10];
    const float* bnb    = (const float*)d_in[11];
    const float* bnm    = (const float*)d_in[12];
    const float* bnv    = (const float*)d_in[13];
    const float* lng    = (const float*)d_in[14];
    const float* lnb    = (const float*)d_in[15];

    const size_t NF = (size_t)NNODES * FDIM;
    unsigned short* xpbf = (unsigned short*)d_ws;     // 25.6 MB (xp, both layers)
    unsigned short* xbf  = xpbf + NF;                 // 25.6 MB (x f16, then h1)
    unsigned short* wt1  = xbf + NF;
    unsigned short* wt2  = wt1 + 65536;
    float* as1   = (float*)(wt2 + 65536);
    float* ad1   = as1 + (size_t)NNODES * 4;
    float* as2   = ad1 + (size_t)NNODES * 4;
    float* ad2   = as2 + NNODES;
    int*   deg    = (int*)(ad2 + NNODES);
    int*   rowptr = deg + NNODES;
    int*   bsum   = rowptr + (NNODES + 1);
    int*   boff   = bsum + SCAN_BLOCKS;
    int*   ssrc   = boff + SCAN_BLOCKS;
    float* outf  = (float*)d_out;

    const dim3 gemm_grid((NNODES + 127) / 128, 2);
    const int node_wave_blocks = (NNODES + 3) / 4;
    const int edge_thread_blocks = (NEDGES + 255) / 256;
    const int cvt_blocks = (int)((NF / 8 + 255) / 256);

    // ---- prep: conversions + CSR ----
    cvt_k<<<cvt_blocks, 256, 0, stream>>>(x, xbf, (int)(NF / 8));
    wprep_k<<<256, 256, 0, stream>>>(W1, wt1);
    wprep_k<<<256, 256, 0, stream>>>(W2, wt2);
    hipMemsetAsync(deg, 0, NNODES * sizeof(int), stream);
    hist_k<<<edge_thread_blocks, 256, 0, stream>>>(ei, deg);
    scanA_k<<<SCAN_BLOCKS, 256, 0, stream>>>(deg, bsum);
    scanB_k<<<1, 256, 0, stream>>>(bsum, boff, rowptr);
    scanC_k<<<SCAN_BLOCKS, 256, 0, stream>>>(deg, boff, rowptr);
    scatter_k<<<edge_thread_blocks, 256, 0, stream>>>(ei, rowptr, deg, ssrc);

    // ---- layer 1 ----
    gemm_mfma<<<gemm_grid, 256, 0, stream>>>(xbf, wt1, xpbf, NNODES);
    aprep_k<4><<<node_wave_blocks, 256, 0, stream>>>(xpbf, atts1, attd1, as1, ad1);
    gather1_k<<<node_wave_blocks, 256, 0, stream>>>(xpbf, as1, ad1, rowptr, ssrc,
                                                    bias1, xbf);

    // ---- layer 2: logits MUST come from xp2 = h1 @ W2 (GEMM output) ----
    gemm_mfma<<<gemm_grid, 256, 0, stream>>>(xbf, wt2, xpbf, NNODES);
    aprep_k<1><<<node_wave_blocks, 256, 0, stream>>>(xpbf, atts2, attd2, as2, ad2);
    gather2_k<<<node_wave_blocks, 256, 0, stream>>>(xpbf, as2, ad2, rowptr, ssrc,
                                                    bias2, bng, bnb, bnm, bnv,
                                                    lng, lnb, outf);
}